// Round 6
// baseline (397.463 us; speedup 1.0000x reference)
//
#include <hip/hip_runtime.h>

// Problem constants (fixed by setup_inputs)
#define NT    8           // timesteps
#define NB    16          // batch
#define FS    262144      // C*H*W (= 2^18)
#define TPB   256         // threads per block
#define BPB   64          // blocks per batch (leader gather = exactly one wave)
#define GRID  (NB*BPB)    // 1024 blocks = 4/CU
#define CHK   4           // float4 chunks/thread -> 16 elems/thread
#define ELB   (TPB*CHK*4) // 4096 elems per block
#define SPIN_CAP (1L<<26)

// Diagnostic probes (this round only): 32 zero-skew exchange rounds each,
// readable as separate dispatch rows in the rocprof table.
#define PR_PASSES 32
#define PSPIN (1L<<20)

// ws layout (zeroed every launch):
//   bsum double[NT][NB][BPB] @ 0      (65536 B) per-block |m| sums, stored -bs
//   dbc  double[NT][NB]      @ 65536  (1024 B)  denom broadcast
#define WS_NEED 66560

__global__ __launch_bounds__(TPB, 4)
void bispike_kernel(const float* __restrict__ x,
                    const float* __restrict__ decay_p,
                    const float* __restrict__ vth_p,
                    const float* __restrict__ W1,
                    const float* __restrict__ b1,
                    const float* __restrict__ W2,
                    const float* __restrict__ b2,
                    const float* __restrict__ att_w,
                    float* __restrict__ out,
                    double* __restrict__ bsum,
                    double* __restrict__ dbc)
{
    const int tid  = threadIdx.x;
    const int lane = tid & 63;
    const int wid  = tid >> 6;
    const int b    = blockIdx.x & 15;
    const int bg   = blockIdx.x >> 4;
    const bool leader = (bg == 0);

    const double dec  = 1.0 / (1.0 + exp(-(double)decay_p[0]));
    const double vth  = (double)vth_p[0];
    const double csub = dec * vth;

    double   u[CHK * 4];
    float4   xv[CHK];
    unsigned sm[NT];

    {
        const float* p = x + (size_t)b * FS + (size_t)bg * ELB + tid * 4;
        #pragma unroll
        for (int k = 0; k < CHK; ++k) xv[k] = *(const float4*)(p + k * (TPB * 4));
    }
    double lsum;
    {
        double n0 = 0.0, n1 = 0.0, n2 = 0.0, n3 = 0.0;
        #pragma unroll
        for (int k = 0; k < CHK; ++k) {
            u[k*4+0] = (double)xv[k].x; n0 += fabs(u[k*4+0]);
            u[k*4+1] = (double)xv[k].y; n1 += fabs(u[k*4+1]);
            u[k*4+2] = (double)xv[k].z; n2 += fabs(u[k*4+2]);
            u[k*4+3] = (double)xv[k].w; n3 += fabs(u[k*4+3]);
        }
        lsum = (n0 + n1) + (n2 + n3);
    }

    __shared__ double dred[4];
    __shared__ double denom_s;

    #pragma unroll 1
    for (int t = 0; t < NT; ++t) {
        if (wid != 0 && t < NT - 1) {
            const float* p = x + ((size_t)(t + 1) * NB + b) * FS
                               + (size_t)bg * ELB + tid * 4;
            #pragma unroll
            for (int k = 0; k < CHK; ++k) xv[k] = *(const float4*)(p + k * (TPB * 4));
        }

        double ls = lsum;
        #pragma unroll
        for (int off = 32; off > 0; off >>= 1)
            ls += __shfl_down(ls, off, 64);
        if (lane == 0) dred[wid] = ls;
        __syncthreads();

        if (tid < 64) {
            const double bs = (dred[0] + dred[1]) + (dred[2] + dred[3]);
            double* slot = bsum + (size_t)(t * NB + b) * BPB;
            if (!leader) {
                if (lane == 0) {
                    __hip_atomic_store(slot + bg, -bs, __ATOMIC_RELAXED,
                                       __HIP_MEMORY_SCOPE_AGENT);
                    double dv; long it = 0;
                    for (;;) {
                        dv = __hip_atomic_load(&dbc[t * NB + b], __ATOMIC_RELAXED,
                                               __HIP_MEMORY_SCOPE_AGENT);
                        if (__double_as_longlong(dv) != 0) break;
                        if (++it > SPIN_CAP) break;
                        __builtin_amdgcn_s_sleep(4);
                    }
                    denom_s = dv;
                }
            } else {
                const bool act = (lane >= 1);
                double v = 0.0; long it = 0;
                for (;;) {
                    if (act)
                        v = __hip_atomic_load(slot + lane, __ATOMIC_RELAXED,
                                              __HIP_MEMORY_SCOPE_AGENT);
                    if (__all(!act || __double_as_longlong(v) != 0)) break;
                    if (++it > SPIN_CAP) break;
                    __builtin_amdgcn_s_sleep(1);
                }
                double tot = (lane == 0) ? bs : -v;
                #pragma unroll
                for (int off = 32; off > 0; off >>= 1)
                    tot += __shfl_down(tot, off, 64);
                if (lane == 0) {
                    const double dn = tot / (double)FS + 1e-6;
                    __hip_atomic_store(&dbc[t * NB + b], dn, __ATOMIC_RELAXED,
                                       __HIP_MEMORY_SCOPE_AGENT);
                    denom_s = dn;
                }
            }
            if (t < NT - 1) {
                const float* p = x + ((size_t)(t + 1) * NB + b) * FS
                                   + (size_t)bg * ELB + tid * 4;
                #pragma unroll
                for (int k = 0; k < CHK; ++k)
                    xv[k] = *(const float4*)(p + k * (TPB * 4));
            }
        }
        __syncthreads();
        const double denom = denom_s;

        const double thr = vth * denom;
        const double a   = dec * (1.0 / denom);
        unsigned smt = 0;
        if (t < NT - 1) {
            double n0 = 0.0, n1 = 0.0, n2 = 0.0, n3 = 0.0;
            #pragma unroll
            for (int k = 0; k < CHK; ++k) {
                const double xn0 = (double)xv[k].x, xn1 = (double)xv[k].y,
                             xn2 = (double)xv[k].z, xn3 = (double)xv[k].w;
                double un;
                bool s0 = (u[k*4+0] >= thr); if (s0) smt |= 1u << (k*4+0);
                un = fma(a, u[k*4+0], xn0); if (s0) un -= csub;
                u[k*4+0] = un; n0 += fabs(un);
                bool s1 = (u[k*4+1] >= thr); if (s1) smt |= 1u << (k*4+1);
                un = fma(a, u[k*4+1], xn1); if (s1) un -= csub;
                u[k*4+1] = un; n1 += fabs(un);
                bool s2 = (u[k*4+2] >= thr); if (s2) smt |= 1u << (k*4+2);
                un = fma(a, u[k*4+2], xn2); if (s2) un -= csub;
                u[k*4+2] = un; n2 += fabs(un);
                bool s3 = (u[k*4+3] >= thr); if (s3) smt |= 1u << (k*4+3);
                un = fma(a, u[k*4+3], xn3); if (s3) un -= csub;
                u[k*4+3] = un; n3 += fabs(un);
            }
            lsum = (n0 + n1) + (n2 + n3);
        } else {
            #pragma unroll
            for (int j = 0; j < CHK * 4; ++j)
                if (u[j] >= thr) smt |= 1u << j;
        }
        sm[t] = smt;
    }

    __shared__ int ired[NT][4];
    #pragma unroll
    for (int t = 0; t < NT; ++t) {
        int c = __popc(sm[t]);
        #pragma unroll
        for (int off = 32; off > 0; off >>= 1)
            c += __shfl_down(c, off, 64);
        if (lane == 0) ired[t][wid] = c;
    }
    __syncthreads();

    __shared__ int totc_s[NT];
    __shared__ double summ_s[NT];

    if (tid < 64) {
        if (!leader) {
            if (lane < NT) {
                int tot = (ired[lane][0] + ired[lane][1])
                        + (ired[lane][2] + ired[lane][3]);
                __hip_atomic_store(&bsum[(size_t)(lane * NB + b) * BPB + bg],
                                   (double)(tot + 1), __ATOMIC_RELAXED,
                                   __HIP_MEMORY_SCOPE_AGENT);
            }
            const bool act = (lane < NT);
            double cv = 1.0; long it = 0;
            for (;;) {
                if (act)
                    cv = __hip_atomic_load(&dbc[lane * NB + b], __ATOMIC_RELAXED,
                                           __HIP_MEMORY_SCOPE_AGENT);
                if (__all(!act || cv < 0.0)) break;
                if (++it > SPIN_CAP) break;
                __builtin_amdgcn_s_sleep(4);
            }
            if (act) totc_s[lane] = (int)(-cv) - 1;
        } else {
            #pragma unroll 1
            for (int t = 0; t < NT; ++t) {
                const bool act = (lane >= 1);
                double v = 0.0; long it = 0;
                for (;;) {
                    if (act)
                        v = __hip_atomic_load(
                                &bsum[(size_t)(t * NB + b) * BPB + lane],
                                __ATOMIC_RELAXED, __HIP_MEMORY_SCOPE_AGENT);
                    if (__all(!act || v > 0.0)) break;
                    if (++it > SPIN_CAP) break;
                    __builtin_amdgcn_s_sleep(1);
                }
                int s = (lane == 0)
                          ? (ired[t][0] + ired[t][1]) + (ired[t][2] + ired[t][3])
                          : (int)v - 1;
                #pragma unroll
                for (int off = 32; off > 0; off >>= 1)
                    s += __shfl_down(s, off, 64);
                if (lane == 0) {
                    totc_s[t] = s;
                    __hip_atomic_store(&dbc[t * NB + b], -(double)(s + 1),
                                       __ATOMIC_RELAXED, __HIP_MEMORY_SCOPE_AGENT);
                }
            }
        }
    }
    __syncthreads();
    if (tid < NT)
        summ_s[tid] = (double)totc_s[tid] / (double)FS;
    __syncthreads();

    __shared__ double h_s[4 * 64];
    __shared__ double wmat_s[NT];
    {
        int nh = tid >> 6, hd = tid & 63;
        double acc = 0.0;
        #pragma unroll
        for (int t = 0; t < NT; ++t)
            acc += summ_s[t] * (double)W1[nh * 512 + hd * 8 + t];
        acc += (double)b1[nh * 64 + hd];
        h_s[tid] = fmax(acc, 0.0);
    }
    __syncthreads();
    if (tid < NT) {
        double w = 0.0;
        for (int nh = 0; nh < 4; ++nh) {
            double macc = 0.0;
            for (int hd = 0; hd < 64; ++hd)
                macc += h_s[nh * 64 + hd] * (double)W2[nh * 512 + tid * 64 + hd];
            macc += (double)b2[nh * 8 + tid];
            w += macc * (double)att_w[nh];
        }
        wmat_s[tid] = w;
    }
    __syncthreads();

    double awr[NT];
    {
        double mx = wmat_s[0];
        #pragma unroll
        for (int t = 1; t < NT; ++t) mx = fmax(mx, wmat_s[t]);
        double ss = 0.0;
        #pragma unroll
        for (int t = 0; t < NT; ++t) { awr[t] = exp(wmat_s[t] - mx); ss += awr[t]; }
        #pragma unroll
        for (int t = 0; t < NT; ++t) awr[t] = awr[t] / ss;
    }

    float* po = out + (size_t)b * FS + (size_t)bg * ELB + tid * 4;
    #pragma unroll
    for (int k = 0; k < CHK; ++k) {
        double o[4] = {0.0, 0.0, 0.0, 0.0};
        #pragma unroll
        for (int t = 0; t < NT; ++t) {
            const unsigned smt = sm[t];
            o[0] += ((smt >> (k * 4 + 0)) & 1) ? awr[t] : 0.0;
            o[1] += ((smt >> (k * 4 + 1)) & 1) ? awr[t] : 0.0;
            o[2] += ((smt >> (k * 4 + 2)) & 1) ? awr[t] : 0.0;
            o[3] += ((smt >> (k * 4 + 3)) & 1) ? awr[t] : 0.0;
        }
        *(float4*)(po + k * (TPB * 4)) =
            make_float4((float)o[0], (float)o[1], (float)o[2], (float)o[3]);
    }
}

// ---- PROBE A: exact replica of the production exchange, zero skew. ----
// 32 rounds of {follower store -> leader 63-lane gather -> bcast -> follower
// 1-lane poll}; pass-encoded values, no resets. Duration/32 = per-round cost.
__global__ __launch_bounds__(64, 8)
void probe_gather(double* __restrict__ bsum, double* __restrict__ dbc)
{
    const int lane = threadIdx.x;
    const int b    = blockIdx.x & 15;
    const int bg   = blockIdx.x >> 4;
    const bool leader = (bg == 0);
    double* slot = bsum + (size_t)b * BPB;

    #pragma unroll 1
    for (int r = 0; r < PR_PASSES; ++r) {
        const double want = -((double)r + 1.5);
        if (!leader) {
            if (lane == 0) {
                __hip_atomic_store(slot + bg, want, __ATOMIC_RELAXED,
                                   __HIP_MEMORY_SCOPE_AGENT);
                double dv; long it = 0;
                for (;;) {
                    dv = __hip_atomic_load(&dbc[b], __ATOMIC_RELAXED,
                                           __HIP_MEMORY_SCOPE_AGENT);
                    if (dv == (double)r + 1.5) break;
                    if (++it > PSPIN) break;
                    __builtin_amdgcn_s_sleep(4);
                }
            }
        } else {
            const bool act = (lane >= 1);
            double v = 0.0; long it = 0;
            for (;;) {
                if (act)
                    v = __hip_atomic_load(slot + lane, __ATOMIC_RELAXED,
                                          __HIP_MEMORY_SCOPE_AGENT);
                if (__all(!act || v == want)) break;
                if (++it > PSPIN) break;
                __builtin_amdgcn_s_sleep(1);
            }
            if (lane == 0)
                __hip_atomic_store(&dbc[b], (double)r + 1.5, __ATOMIC_RELAXED,
                                   __HIP_MEMORY_SCOPE_AGENT);
        }
    }
}

// ---- PROBE B: atomicAdd fan-in + padded monotone counter, zero skew. ----
// Every block: fp64 atomicAdd(sum) + int atomicAdd(ctr), then poll
// ctr == 64*(r+1). No leader, no resets. Duration/32 = per-round cost.
__global__ __launch_bounds__(64, 8)
void probe_atomic(char* __restrict__ base)
{
    const int lane = threadIdx.x;
    const int b    = blockIdx.x & 15;
    double* sum = (double*)(base + (size_t)b * 256);
    int*    ctr = (int*)(base + 8192 + (size_t)b * 256);

    #pragma unroll 1
    for (int r = 0; r < PR_PASSES; ++r) {
        if (lane == 0) {
            __hip_atomic_fetch_add(sum, 1.0, __ATOMIC_RELAXED,
                                   __HIP_MEMORY_SCOPE_AGENT);
            __hip_atomic_fetch_add(ctr, 1, __ATOMIC_RELAXED,
                                   __HIP_MEMORY_SCOPE_AGENT);
            int c; long it = 0;
            for (;;) {
                c = __hip_atomic_load(ctr, __ATOMIC_RELAXED,
                                      __HIP_MEMORY_SCOPE_AGENT);
                if (c >= 64 * (r + 1)) break;
                if (++it > PSPIN) break;
                __builtin_amdgcn_s_sleep(2);
            }
            double sv = __hip_atomic_load(sum, __ATOMIC_RELAXED,
                                          __HIP_MEMORY_SCOPE_AGENT);
            asm volatile("" :: "v"(sv));   // keep the value-read live
        }
    }
}

__global__ void diag_kernel(float* out, int code) {
    out[0] = 100000.0f + (float)code;
}

extern "C" void kernel_launch(void* const* d_in, const int* in_sizes, int n_in,
                              void* d_out, int out_size, void* d_ws, size_t ws_size,
                              hipStream_t stream) {
    const float* x     = (const float*)d_in[0];
    const float* decay = (const float*)d_in[1];
    const float* vth   = (const float*)d_in[2];
    const float* W1    = (const float*)d_in[3];
    const float* b1    = (const float*)d_in[4];
    const float* W2    = (const float*)d_in[5];
    const float* b2    = (const float*)d_in[6];
    const float* att   = (const float*)d_in[7];
    float* out = (float*)d_out;

    if (ws_size < WS_NEED) {
        diag_kernel<<<1, 1, 0, stream>>>(out, 999);
        return;
    }

    double* bsum = (double*)d_ws;
    double* dbc  = (double*)((char*)d_ws + 65536);

    hipMemsetAsync(d_ws, 0, WS_NEED, stream);

    hipGetLastError();  // clear stale error
    bispike_kernel<<<dim3(GRID), dim3(TPB), 0, stream>>>(
        x, decay, vth, W1, b1, W2, b2, att, out, bsum, dbc);
    hipError_t err = hipGetLastError();
    if (err != hipSuccess) {
        diag_kernel<<<1, 1, 0, stream>>>(out, (int)err);
        return;
    }

    // ---- diagnostic probes (this round only; out already written) ----
    hipMemsetAsync(d_ws, 0, WS_NEED, stream);
    probe_gather<<<dim3(GRID), dim3(64), 0, stream>>>(bsum, dbc);
    hipMemsetAsync(d_ws, 0, WS_NEED, stream);
    probe_atomic<<<dim3(GRID), dim3(64), 0, stream>>>((char*)d_ws);
}